// Round 1
// baseline (698.151 us; speedup 1.0000x reference)
//
#include <hip/hip_runtime.h>
#include <math.h>

// Problem constants: hidden [2,32,1024] f32, encoder_outputs [32,4096,1024] f32,
// mask [32,4096] int. Outputs: context [32,1024] f32 then attn [32,4096] f32.
#define B_ 32
#define S_ 4096
#define H_ 1024
#define NBLK 64                               // blocks per batch in pass 1 (was 16)
#define ROWS_PER_BLOCK (S_ / NBLK)            // 64
#define NWAVE 4
#define ROWS_PER_WAVE (ROWS_PER_BLOCK / NWAVE) // 16
#define NEG_INF_ -1.0e9f

// Pass 1: one streaming pass over encoder_outputs. Each wave handles 16 rows:
// depth-1 prefetched row loads, butterfly-reduced dot, online softmax with
// wave-uniform conditional rescale (exact), 16-VGPR/lane context fragment.
// Block combines its 4 waves in LDS -> one partial (M, L, ctx[1024]) per block.
// 2048 blocks total -> 8 blocks/CU schedulable; launch_bounds(256,4) caps VGPR
// at 128 so 4 blocks/CU are resident (16 waves/CU = 4/SIMD).
__global__ __launch_bounds__(256, 4) void attn_pass1(
    const float* __restrict__ hidden,   // [2,B,H] — use layer 1 (last)
    const float* __restrict__ enc,      // [B,S,H]
    const int*   __restrict__ mask,     // [B,S]
    float* __restrict__ scores,         // raw scores -> attn slot of d_out [B,S]
    float* __restrict__ part_ctx,       // ws: [B*NBLK, H]
    float* __restrict__ part_ml)        // ws: [B*NBLK, 2] = (M, L)
{
    const int blk  = blockIdx.x;        // 0 .. B*NBLK-1
    const int b    = blk / NBLK;
    const int cb   = blk % NBLK;
    const int tid  = threadIdx.x;
    const int wave = tid >> 6;
    const int lane = tid & 63;

    // h fragment: lane holds elems {4L..4L+3, 256+4L.., 512+4L.., 768+4L..}
    const float4* h4 = (const float4*)(hidden + (size_t)(B_ + b) * H_); // layer -1
    const float4 hf0 = h4[lane];
    const float4 hf1 = h4[lane + 64];
    const float4 hf2 = h4[lane + 128];
    const float4 hf3 = h4[lane + 192];

    float m = -INFINITY;
    float l = 0.0f;
    float4 c0 = {0.f, 0.f, 0.f, 0.f};
    float4 c1 = c0, c2 = c0, c3 = c0;
    float myscore = 0.0f;               // lane r (r<16) keeps row r's score

    const int    row0  = cb * ROWS_PER_BLOCK + wave * ROWS_PER_WAVE;
    const float* encb  = enc  + (size_t)b * S_ * H_;
    const int*   maskb = mask + (size_t)b * S_;

    // prefetch row 0
    const float4* rp = (const float4*)(encb + (size_t)row0 * H_);
    float4 n0 = rp[lane];
    float4 n1 = rp[lane + 64];
    float4 n2 = rp[lane + 128];
    float4 n3 = rp[lane + 192];

    for (int r = 0; r < ROWS_PER_WAVE; ++r) {
        const float4 r0 = n0, r1 = n1, r2 = n2, r3 = n3;
        // issue next row's loads BEFORE the reduce chain so HBM latency
        // overlaps the shfl/exp critical path
        if (r + 1 < ROWS_PER_WAVE) {
            const float4* np = (const float4*)(encb + (size_t)(row0 + r + 1) * H_);
            n0 = np[lane];
            n1 = np[lane + 64];
            n2 = np[lane + 128];
            n3 = np[lane + 192];
        }

        float dot = r0.x * hf0.x + r0.y * hf0.y + r0.z * hf0.z + r0.w * hf0.w;
        dot += r1.x * hf1.x + r1.y * hf1.y + r1.z * hf1.z + r1.w * hf1.w;
        dot += r2.x * hf2.x + r2.y * hf2.y + r2.z * hf2.z + r2.w * hf2.w;
        dot += r3.x * hf3.x + r3.y * hf3.y + r3.z * hf3.z + r3.w * hf3.w;

        #pragma unroll
        for (int off = 32; off >= 1; off >>= 1)
            dot += __shfl_xor(dot, off, 64);   // all 64 lanes end with the sum

        const int s = row0 + r;
        const float score = (maskb[s] != 0) ? dot : NEG_INF_;
        if (r == lane) myscore = score;

        // online softmax, wave-uniform conditional rescale (score is uniform
        // across lanes after the butterfly -> s_cbranch, no divergence).
        // Exact: identical math to unconditional form when score <= m.
        if (score > m) {
            const float scale = __expf(m - score);   // exp(-inf)=0 handles init
            l *= scale;
            c0.x *= scale; c0.y *= scale; c0.z *= scale; c0.w *= scale;
            c1.x *= scale; c1.y *= scale; c1.z *= scale; c1.w *= scale;
            c2.x *= scale; c2.y *= scale; c2.z *= scale; c2.w *= scale;
            c3.x *= scale; c3.y *= scale; c3.z *= scale; c3.w *= scale;
            m = score;
        }
        const float p = __expf(score - m);
        l += p;
        c0.x += p * r0.x;  c0.y += p * r0.y;  c0.z += p * r0.z;  c0.w += p * r0.w;
        c1.x += p * r1.x;  c1.y += p * r1.y;  c1.z += p * r1.z;  c1.w += p * r1.w;
        c2.x += p * r2.x;  c2.y += p * r2.y;  c2.z += p * r2.z;  c2.w += p * r2.w;
        c3.x += p * r3.x;  c3.y += p * r3.y;  c3.z += p * r3.z;  c3.w += p * r3.w;
    }

    // raw-score store: lane r (r<16) holds score of row row0+r
    if (lane < ROWS_PER_WAVE)
        scores[(size_t)b * S_ + row0 + lane] = myscore;

    // combine the 4 waves of this block in LDS
    __shared__ float lds_ctx[NWAVE][H_];   // 16 KB
    __shared__ float lds_m[NWAVE];
    __shared__ float lds_l[NWAVE];
    float4* dst = (float4*)lds_ctx[wave];
    dst[lane]       = c0;
    dst[lane + 64]  = c1;
    dst[lane + 128] = c2;
    dst[lane + 192] = c3;
    if (lane == 0) { lds_m[wave] = m; lds_l[wave] = l; }
    __syncthreads();

    const float M  = fmaxf(fmaxf(lds_m[0], lds_m[1]), fmaxf(lds_m[2], lds_m[3]));
    const float w0 = __expf(lds_m[0] - M);
    const float w1 = __expf(lds_m[1] - M);
    const float w2 = __expf(lds_m[2] - M);
    const float w3 = __expf(lds_m[3] - M);

    const int e = tid * 4;                 // 256 threads x 4 = 1024 elems
    const float4 a0 = *(const float4*)&lds_ctx[0][e];
    const float4 a1 = *(const float4*)&lds_ctx[1][e];
    const float4 a2 = *(const float4*)&lds_ctx[2][e];
    const float4 a3 = *(const float4*)&lds_ctx[3][e];
    float4 o;
    o.x = a0.x * w0 + a1.x * w1 + a2.x * w2 + a3.x * w3;
    o.y = a0.y * w0 + a1.y * w1 + a2.y * w2 + a3.y * w3;
    o.z = a0.z * w0 + a1.z * w1 + a2.z * w2 + a3.z * w3;
    o.w = a0.w * w0 + a1.w * w1 + a2.w * w2 + a3.w * w3;
    *(float4*)&part_ctx[(size_t)blk * H_ + e] = o;

    if (tid == 0) {
        const float L = lds_l[0] * w0 + lds_l[1] * w1 + lds_l[2] * w2 + lds_l[3] * w3;
        part_ml[blk * 2]     = M;
        part_ml[blk * 2 + 1] = L;
    }
}

// Pass 2: combine NBLK partials per batch; write context; normalize the raw
// scores in d_out into attn (in place). grid = (B, 5): y==0 -> context;
// y in 1..4 -> attn quarter-chunks of 1024. No w[NBLK] register array
// (NBLK=64 would spill): recompute the exp per partial — part_ml is L2-hot.
__global__ __launch_bounds__(256) void attn_pass2(
    const float* __restrict__ part_ctx,  // [B*NBLK, H]
    const float* __restrict__ part_ml,   // [B*NBLK, 2]
    float* __restrict__ out_ctx,         // [B,H]
    float* __restrict__ attn)            // [B,S], holds raw scores on entry
{
    const int b    = blockIdx.x;
    const int part = blockIdx.y;
    const int tid  = threadIdx.x;

    float M = -INFINITY;
    #pragma unroll 8
    for (int p = 0; p < NBLK; ++p)
        M = fmaxf(M, part_ml[(b * NBLK + p) * 2]);

    float L = 0.0f;
    #pragma unroll 8
    for (int p = 0; p < NBLK; ++p)
        L += part_ml[(b * NBLK + p) * 2 + 1] *
             __expf(part_ml[(b * NBLK + p) * 2] - M);
    const float invL = 1.0f / L;

    if (part == 0) {
        const int e = tid * 4;
        float4 acc = {0.f, 0.f, 0.f, 0.f};
        #pragma unroll 4
        for (int p = 0; p < NBLK; ++p) {
            const float w = __expf(part_ml[(b * NBLK + p) * 2] - M);
            const float4 v = *(const float4*)&part_ctx[(size_t)(b * NBLK + p) * H_ + e];
            acc.x += v.x * w;  acc.y += v.y * w;
            acc.z += v.z * w;  acc.w += v.w * w;
        }
        acc.x *= invL; acc.y *= invL; acc.z *= invL; acc.w *= invL;
        *(float4*)&out_ctx[(size_t)b * H_ + e] = acc;
    } else {
        const size_t s0 = (size_t)b * S_ + (size_t)(part - 1) * 1024 + tid * 4;
        float4 sc = *(const float4*)&attn[s0];
        sc.x = __expf(sc.x - M) * invL;
        sc.y = __expf(sc.y - M) * invL;
        sc.z = __expf(sc.z - M) * invL;
        sc.w = __expf(sc.w - M) * invL;
        *(float4*)&attn[s0] = sc;
    }
}

extern "C" void kernel_launch(void* const* d_in, const int* in_sizes, int n_in,
                              void* d_out, int out_size, void* d_ws, size_t ws_size,
                              hipStream_t stream) {
    (void)in_sizes; (void)n_in; (void)out_size; (void)ws_size;
    const float* hidden = (const float*)d_in[0];  // [2,B,H]
    const float* enc    = (const float*)d_in[1];  // [B,S,H]
    const int*   mask   = (const int*)d_in[2];    // [B,S]

    float* out      = (float*)d_out;
    float* out_ctx  = out;                        // [B,H]
    float* attn     = out + (size_t)B_ * H_;      // [B,S]

    float* part_ctx = (float*)d_ws;                        // B*NBLK*H floats (8 MB)
    float* part_ml  = part_ctx + (size_t)B_ * NBLK * H_;   // B*NBLK*2 floats

    attn_pass1<<<dim3(B_ * NBLK), dim3(256), 0, stream>>>(
        hidden, enc, mask, attn, part_ctx, part_ml);
    attn_pass2<<<dim3(B_, 5), dim3(256), 0, stream>>>(
        part_ctx, part_ml, out_ctx, attn);
}

// Round 2
// 647.683 us; speedup vs baseline: 1.0779x; 1.0779x over previous
//
#include <hip/hip_runtime.h>
#include <math.h>

// Problem constants: hidden [2,32,1024] f32, encoder_outputs [32,4096,1024] f32,
// mask [32,4096] int. Outputs: context [32,1024] f32 then attn [32,4096] f32.
#define B_ 32
#define S_ 4096
#define H_ 1024
#define NBLK 64                               // blocks per batch in pass 1
#define ROWS_PER_BLOCK (S_ / NBLK)            // 64
#define NWAVE 4
#define ROWS_PER_WAVE (ROWS_PER_BLOCK / NWAVE) // 16
#define NEG_INF_ -1.0e9f

// Pass 1: stream only the UNMASKED rows of encoder_outputs (~50% of bytes).
// Masked rows contribute exactly 0 to context (exp(-1e9-M) underflows to 0.0f
// in fp32, same as the reference), and their attn entries are produced in
// pass 2 from the raw -1e9 score without needing enc. Mask bits for the
// wave's 16 rows are preloaded once via __ballot (one coalesced load), so the
// row loop has NO per-row mask VMEM load and the skip branch is wave-uniform
// (s_cbranch, zero divergence).
__global__ __launch_bounds__(256) void attn_pass1(
    const float* __restrict__ hidden,   // [2,B,H] — use layer 1 (last)
    const float* __restrict__ enc,      // [B,S,H]
    const int*   __restrict__ mask,     // [B,S]
    float* __restrict__ scores,         // raw scores -> attn slot of d_out [B,S]
    float* __restrict__ part_ctx,       // ws: [B*NBLK, H]
    float* __restrict__ part_ml)        // ws: [B*NBLK, 2] = (M, L)
{
    const int blk  = blockIdx.x;        // 0 .. B*NBLK-1
    const int b    = blk / NBLK;
    const int cb   = blk % NBLK;
    const int tid  = threadIdx.x;
    const int wave = tid >> 6;
    const int lane = tid & 63;

    // h fragment: lane holds elems {4L..4L+3, 256+4L.., 512+4L.., 768+4L..}
    const float4* h4 = (const float4*)(hidden + (size_t)(B_ + b) * H_); // layer -1
    const float4 hf0 = h4[lane];
    const float4 hf1 = h4[lane + 64];
    const float4 hf2 = h4[lane + 128];
    const float4 hf3 = h4[lane + 192];

    float m = -INFINITY;
    float l = 0.0f;
    float4 c0 = {0.f, 0.f, 0.f, 0.f};
    float4 c1 = c0, c2 = c0, c3 = c0;
    float myscore = NEG_INF_;           // lane r (r<16) keeps row r's score

    const int    row0  = cb * ROWS_PER_BLOCK + wave * ROWS_PER_WAVE;
    const float* encb  = enc  + (size_t)b * S_ * H_;
    const int*   maskb = mask + (size_t)b * S_;

    // one coalesced mask read -> 16 valid bits in an SGPR-resident ballot
    const unsigned long long mb =
        __ballot((lane < ROWS_PER_WAVE) && (maskb[row0 + lane] != 0));

    for (int r = 0; r < ROWS_PER_WAVE; ++r) {
        if (!((mb >> r) & 1ull)) continue;   // wave-uniform skip: no load at all

        const float4* row4 = (const float4*)(encb + (size_t)(row0 + r) * H_);
        const float4 r0 = row4[lane];
        const float4 r1 = row4[lane + 64];
        const float4 r2 = row4[lane + 128];
        const float4 r3 = row4[lane + 192];

        float dot = r0.x * hf0.x + r0.y * hf0.y + r0.z * hf0.z + r0.w * hf0.w;
        dot += r1.x * hf1.x + r1.y * hf1.y + r1.z * hf1.z + r1.w * hf1.w;
        dot += r2.x * hf2.x + r2.y * hf2.y + r2.z * hf2.z + r2.w * hf2.w;
        dot += r3.x * hf3.x + r3.y * hf3.y + r3.z * hf3.z + r3.w * hf3.w;

        #pragma unroll
        for (int off = 32; off >= 1; off >>= 1)
            dot += __shfl_xor(dot, off, 64);   // all 64 lanes end with the sum

        const float score = dot;               // unmasked row: score is real
        if (r == lane) myscore = score;

        // online softmax, wave-uniform conditional rescale (score is uniform
        // across lanes after the butterfly -> s_cbranch, no divergence).
        if (score > m) {
            const float scale = __expf(m - score);   // exp(-inf)=0 handles init
            l *= scale;
            c0.x *= scale; c0.y *= scale; c0.z *= scale; c0.w *= scale;
            c1.x *= scale; c1.y *= scale; c1.z *= scale; c1.w *= scale;
            c2.x *= scale; c2.y *= scale; c2.z *= scale; c2.w *= scale;
            c3.x *= scale; c3.y *= scale; c3.z *= scale; c3.w *= scale;
            m = score;
        }
        const float p = __expf(score - m);
        l += p;
        c0.x += p * r0.x;  c0.y += p * r0.y;  c0.z += p * r0.z;  c0.w += p * r0.w;
        c1.x += p * r1.x;  c1.y += p * r1.y;  c1.z += p * r1.z;  c1.w += p * r1.w;
        c2.x += p * r2.x;  c2.y += p * r2.y;  c2.z += p * r2.z;  c2.w += p * r2.w;
        c3.x += p * r3.x;  c3.y += p * r3.y;  c3.z += p * r3.z;  c3.w += p * r3.w;
    }

    // all-masked chunk: l=0, c=0; clamp m so pass2's weight exp(m-M) -> 0
    if (m == -INFINITY) m = NEG_INF_;

    // raw-score store: lane r (r<16) holds row row0+r's score (-1e9 if masked)
    if (lane < ROWS_PER_WAVE)
        scores[(size_t)b * S_ + row0 + lane] = myscore;

    // combine the 4 waves of this block in LDS
    __shared__ float lds_ctx[NWAVE][H_];   // 16 KB
    __shared__ float lds_m[NWAVE];
    __shared__ float lds_l[NWAVE];
    float4* dst = (float4*)lds_ctx[wave];
    dst[lane]       = c0;
    dst[lane + 64]  = c1;
    dst[lane + 128] = c2;
    dst[lane + 192] = c3;
    if (lane == 0) { lds_m[wave] = m; lds_l[wave] = l; }
    __syncthreads();

    const float M  = fmaxf(fmaxf(lds_m[0], lds_m[1]), fmaxf(lds_m[2], lds_m[3]));
    const float w0 = __expf(lds_m[0] - M);
    const float w1 = __expf(lds_m[1] - M);
    const float w2 = __expf(lds_m[2] - M);
    const float w3 = __expf(lds_m[3] - M);

    const int e = tid * 4;                 // 256 threads x 4 = 1024 elems
    const float4 a0 = *(const float4*)&lds_ctx[0][e];
    const float4 a1 = *(const float4*)&lds_ctx[1][e];
    const float4 a2 = *(const float4*)&lds_ctx[2][e];
    const float4 a3 = *(const float4*)&lds_ctx[3][e];
    float4 o;
    o.x = a0.x * w0 + a1.x * w1 + a2.x * w2 + a3.x * w3;
    o.y = a0.y * w0 + a1.y * w1 + a2.y * w2 + a3.y * w3;
    o.z = a0.z * w0 + a1.z * w1 + a2.z * w2 + a3.z * w3;
    o.w = a0.w * w0 + a1.w * w1 + a2.w * w2 + a3.w * w3;
    *(float4*)&part_ctx[(size_t)blk * H_ + e] = o;

    if (tid == 0) {
        const float L = lds_l[0] * w0 + lds_l[1] * w1 + lds_l[2] * w2 + lds_l[3] * w3;
        part_ml[blk * 2]     = M;
        part_ml[blk * 2 + 1] = L;
    }
}

// Pass 2: combine NBLK partials per batch; write context; normalize the raw
// scores in d_out into attn (in place). grid = (B, 5): y==0 -> context;
// y in 1..4 -> attn quarter-chunks of 1024. No w[NBLK] register array
// (NBLK=64 would spill): recompute the exp per partial — part_ml is L2-hot.
__global__ __launch_bounds__(256) void attn_pass2(
    const float* __restrict__ part_ctx,  // [B*NBLK, H]
    const float* __restrict__ part_ml,   // [B*NBLK, 2]
    float* __restrict__ out_ctx,         // [B,H]
    float* __restrict__ attn)            // [B,S], holds raw scores on entry
{
    const int b    = blockIdx.x;
    const int part = blockIdx.y;
    const int tid  = threadIdx.x;

    float M = -INFINITY;
    #pragma unroll 8
    for (int p = 0; p < NBLK; ++p)
        M = fmaxf(M, part_ml[(b * NBLK + p) * 2]);

    float L = 0.0f;
    #pragma unroll 8
    for (int p = 0; p < NBLK; ++p)
        L += part_ml[(b * NBLK + p) * 2 + 1] *
             __expf(part_ml[(b * NBLK + p) * 2] - M);
    const float invL = 1.0f / L;

    if (part == 0) {
        const int e = tid * 4;
        float4 acc = {0.f, 0.f, 0.f, 0.f};
        #pragma unroll 4
        for (int p = 0; p < NBLK; ++p) {
            const float w = __expf(part_ml[(b * NBLK + p) * 2] - M);
            const float4 v = *(const float4*)&part_ctx[(size_t)(b * NBLK + p) * H_ + e];
            acc.x += v.x * w;  acc.y += v.y * w;
            acc.z += v.z * w;  acc.w += v.w * w;
        }
        acc.x *= invL; acc.y *= invL; acc.z *= invL; acc.w *= invL;
        *(float4*)&out_ctx[(size_t)b * H_ + e] = acc;
    } else {
        const size_t s0 = (size_t)b * S_ + (size_t)(part - 1) * 1024 + tid * 4;
        float4 sc = *(const float4*)&attn[s0];
        sc.x = __expf(sc.x - M) * invL;
        sc.y = __expf(sc.y - M) * invL;
        sc.z = __expf(sc.z - M) * invL;
        sc.w = __expf(sc.w - M) * invL;
        *(float4*)&attn[s0] = sc;
    }
}

extern "C" void kernel_launch(void* const* d_in, const int* in_sizes, int n_in,
                              void* d_out, int out_size, void* d_ws, size_t ws_size,
                              hipStream_t stream) {
    (void)in_sizes; (void)n_in; (void)out_size; (void)ws_size;
    const float* hidden = (const float*)d_in[0];  // [2,B,H]
    const float* enc    = (const float*)d_in[1];  // [B,S,H]
    const int*   mask   = (const int*)d_in[2];    // [B,S]

    float* out      = (float*)d_out;
    float* out_ctx  = out;                        // [B,H]
    float* attn     = out + (size_t)B_ * H_;      // [B,S]

    float* part_ctx = (float*)d_ws;                        // B*NBLK*H floats (8 MB)
    float* part_ml  = part_ctx + (size_t)B_ * NBLK * H_;   // B*NBLK*2 floats

    attn_pass1<<<dim3(B_ * NBLK), dim3(256), 0, stream>>>(
        hidden, enc, mask, attn, part_ctx, part_ml);
    attn_pass2<<<dim3(B_, 5), dim3(256), 0, stream>>>(
        part_ctx, part_ml, out_ctx, attn);
}